// Round 9
// baseline (6217.457 us; speedup 1.0000x reference)
//
#include <hip/hip_runtime.h>
#include <hip/hip_bf16.h>

typedef unsigned short u16;
typedef __attribute__((ext_vector_type(8))) __bf16 bf16x8;
typedef __attribute__((ext_vector_type(4))) float f32x4;
typedef __attribute__((ext_vector_type(4))) unsigned short u16x4;

#define BB 8
#define SS 2048
#define DD 768
#define DFF 3072
#define NL 12
#define ROWS (BB*SS)
#define VOC 32000

__device__ __forceinline__ u16 f2bf(float f){
  union { float f; unsigned u; } v; v.f = f;
  unsigned u = v.u;
  u += 0x7FFF + ((u >> 16) & 1);
  return (u16)(u >> 16);
}

// ---------- setup kernels ----------
__global__ void k_embed(const int* __restrict__ tok, const float4* __restrict__ emb,
                        float4* __restrict__ x){
  int i = blockIdx.x*256 + threadIdx.x;
  if (i >= ROWS*192) return;
  int row = i/192, c = i - row*192;
  x[i] = emb[(long)tok[row]*192 + c];
}

__global__ void k_dftD(u16* __restrict__ out){ // [1536][768]: rows<768 cos, >=768 sin
  int i = blockIdx.x*256 + threadIdx.x;
  if (i >= 1536*768) return;
  int n = i/768, k = i - n*768;
  int nn = (n < 768) ? n : n - 768;
  int m = (nn*k) % 768;
  float a = 2.0f*(float)m/768.0f;
  out[i] = f2bf((n < 768) ? cospif(a) : sinpif(a));
}

__global__ void k_dftS(u16* __restrict__ out){ // [2048][4096]: cols<2048 cos, >=2048 -sin
  int i = blockIdx.x*256 + threadIdx.x;
  if (i >= 2048*4096) return;
  int t = i >> 12, s = i & 4095;
  int ss = (s < 2048) ? s : s - 2048;
  int m = (t*ss) & 2047;
  float a = (float)m * (2.0f/2048.0f);
  out[i] = f2bf((s < 2048) ? cospif(a) : -sinpif(a));
}

// one wave per row of 768
__global__ void k_ln(const float* __restrict__ x, const float* __restrict__ g,
                     const float* __restrict__ b, u16* __restrict__ h){
  int row = blockIdx.x*4 + (threadIdx.x >> 6);
  int lane = threadIdx.x & 63;
  const float* xr = x + (long)row*DD;
  float v[12];
  float s = 0.f;
  #pragma unroll
  for (int j = 0; j < 12; j++){ v[j] = xr[lane + j*64]; s += v[j]; }
  #pragma unroll
  for (int o = 32; o > 0; o >>= 1) s += __shfl_xor(s, o);
  float mu = s * (1.0f/768.0f);
  float q = 0.f;
  #pragma unroll
  for (int j = 0; j < 12; j++){ float d = v[j]-mu; q += d*d; }
  #pragma unroll
  for (int o = 32; o > 0; o >>= 1) q += __shfl_xor(q, o);
  float rs = rsqrtf(q * (1.0f/768.0f) + 1e-5f);
  u16* hr = h + (long)row*DD;
  #pragma unroll
  for (int j = 0; j < 12; j++){
    int e = lane + j*64;
    hr[e] = f2bf((v[j]-mu)*rs*g[e] + b[e]);
  }
}

// f32 [R][C] -> bf16 [C][R]
__global__ void k_transpose_cvt(const float* __restrict__ src, u16* __restrict__ dst,
                                int R, int C){
  __shared__ float t[32][33];
  int bx = blockIdx.x*32, by = blockIdx.y*32;
  int tx = threadIdx.x, ty = threadIdx.y;
  #pragma unroll
  for (int i = 0; i < 4; i++) t[ty+i*8][tx] = src[(long)(by+ty+i*8)*C + bx+tx];
  __syncthreads();
  #pragma unroll
  for (int i = 0; i < 4; i++) dst[(long)(bx+ty+i*8)*R + by+tx] = f2bf(t[tx][ty+i*8]);
}

#define EPI_DFT  0
#define EPI_ADDX 1
#define EPI_GELU 2

// ---------- 128^2 / BK=64 double-buffered GEMM, 64 KiB LDS -> 2 blocks/CU ----------
// Same R7-proven data path (128B LDS rows, (fr&7) XOR swizzle, linear gload_lds dest with
// pre-swizzled source), same 2-phase schedule (1 full-drain barrier per K-tile). The win
// vs R7 is occupancy: 2 independent blocks/CU overlap each other's drain (m114/m97).
template<int EPI>
__global__ __launch_bounds__(256, 2)
void k_gemm128(const u16* __restrict__ A, const u16* __restrict__ BT,
               int Mt, int N, int K, int NT, long aBS, long btBS, int rowOffPerZ,
               float* __restrict__ X, const float* __restrict__ bias,
               u16* __restrict__ OUT){
  __shared__ __align__(16) u16 lds[2][2][128][64];   // [buf][A/B][row][col] = 64 KiB
  const int tid  = threadIdx.x;
  const int wave = tid >> 6, lane = tid & 63;
  const int wm = wave >> 1, wn = wave & 1;           // 2x2 waves, 64x64 per wave

  const int bz = blockIdx.z;
  const u16* Ab = A + (long)bz*aBS;
  const u16* Bb = BT + (long)bz*btBS;
  const int rowOff = bz*rowOffPerZ;

  // XCD-aware swizzle (gridDim.x % 8 == 0 at all call sites)
  const int nwg = gridDim.x;
  const int id  = blockIdx.x;
  const int sw  = (id & 7) * (nwg >> 3) + (id >> 3);
  const int bm = (sw % Mt) << 7;
  const int bn = (sw / Mt) << 7;

  const int fr   = lane & 15;
  const int fks8 = (lane >> 4) << 3;
  const int swz  = (fr & 7) << 3;                    // read-side XOR (elements)

  const int sRow8 = lane >> 3;                       // row 0..7 within an 8-row chunk
  const int sCol  = ((lane & 7) ^ (sRow8 & 7)) << 3; // pre-swizzled src col chunk (elems)

  f32x4 acc[4][4] = {};
  bf16x8 aF[4][2], bF[4][2];

  auto stage = [&](int tile){               // full tile: A(4 loads/wave) + B(4 loads/wave)
    if (tile >= NT) return;
    #pragma unroll
    for (int m = 0; m < 2; ++m){
      const u16* src = m ? Bb : Ab;
      const int rbase = m ? bn : bm;
      #pragma unroll
      for (int j = 0; j < 4; ++j){
        const int r0 = j*32 + wave*8;       // wave-uniform 8-row chunk
        const u16* s0 = src + (long)(rbase + r0 + sRow8)*K + (tile << 6) + sCol;
        u16* d0 = &lds[tile & 1][m][r0][0];
        __builtin_amdgcn_global_load_lds((__attribute__((address_space(1))) void*)(s0),
                                         (__attribute__((address_space(3))) void*)(d0), 16, 0, 0);
      }
    }
  };

  auto readA = [&](int c){
    const u16* base = &lds[c][0][wm << 6][0];
    #pragma unroll
    for (int mm = 0; mm < 4; ++mm)
      #pragma unroll
      for (int ks = 0; ks < 2; ++ks)
        aF[mm][ks] = *(const bf16x8*)&base[((mm<<4) + fr)*64 + (((ks<<5) + fks8) ^ swz)];
  };
  auto readB = [&](int c){
    const u16* base = &lds[c][1][wn << 6][0];
    #pragma unroll
    for (int nn = 0; nn < 4; ++nn)
      #pragma unroll
      for (int ks = 0; ks < 2; ++ks)
        bF[nn][ks] = *(const bf16x8*)&base[((nn<<4) + fr)*64 + (((ks<<5) + fks8) ^ swz)];
  };

  stage(0);
  __syncthreads();                           // full drain: tile 0 resident

  int c = 0;
  for (int T = 0; T < NT; ++T, c ^= 1){
    stage(T + 1);                            // async into buf c^1, drained by end barrier
    readA(c); readB(c);
    __builtin_amdgcn_s_setprio(1);
    #pragma unroll
    for (int mm = 0; mm < 4; ++mm)
      #pragma unroll
      for (int nn = 0; nn < 4; ++nn)
        #pragma unroll
        for (int ks = 0; ks < 2; ++ks)
          acc[mm][nn] = __builtin_amdgcn_mfma_f32_16x16x32_bf16(
              aF[mm][ks], bF[nn][ks], acc[mm][nn], 0, 0, 0);
    __builtin_amdgcn_s_setprio(0);
    __syncthreads();                         // drains vmcnt+lgkmcnt: T+1 resident, reads done
  }

  const int er = (lane >> 4) << 2, ec = lane & 15;
  #pragma unroll
  for (int mi = 0; mi < 4; ++mi){
    int row = bm + (wm << 6) + (mi << 4) + er;
    #pragma unroll
    for (int ni = 0; ni < 4; ++ni){
      int col = bn + (wn << 6) + (ni << 4) + ec;
      f32x4 v = acc[mi][ni];
      if constexpr (EPI == EPI_ADDX){
        float bv = bias ? bias[col] : 0.0f;
        #pragma unroll
        for (int r = 0; r < 4; r++)
          X[(long)(rowOff + row + r)*N + col] += v[r] + bv;
      } else if constexpr (EPI == EPI_GELU){
        float bv = bias[col];
        #pragma unroll
        for (int r = 0; r < 4; r++){
          float tt = v[r] + bv;
          OUT[(long)(row + r)*N + col] = f2bf(0.5f*tt*(1.0f + erff(tt*0.70710678118654752f)));
        }
      } else { // EPI_DFT: write transposed per batch into F[b][d][slot]
        int bb = row >> 11, s = row & 2047;
        int d, slot;
        if (col < 768){ d = col; slot = s; } else { d = col - 768; slot = 2048 + s; }
        u16x4 pk;
        #pragma unroll
        for (int r = 0; r < 4; r++) pk[r] = f2bf(v[r]);
        *(u16x4*)&OUT[((long)(bb*768 + d))*4096 + slot] = pk;
      }
    }
  }
}

__global__ void k_logits(const float* __restrict__ x, const float* __restrict__ Wout,
                         const float* __restrict__ bout, float* __restrict__ out){
  __shared__ float xl[8][768];
  int tid = threadIdx.x;
  for (int i = tid; i < 8*768; i += 256){
    int b = i/768, d = i - b*768;
    xl[b][d] = x[((long)(b*2048 + 2047))*768 + d];
  }
  __syncthreads();
  int v = blockIdx.x*256 + tid;
  float acc[8];
  float bv = bout[v];
  #pragma unroll
  for (int b = 0; b < 8; b++) acc[b] = bv;
  for (int d = 0; d < 768; d++){
    float w = Wout[(long)d*VOC + v];
    #pragma unroll
    for (int b = 0; b < 8; b++) acc[b] += xl[b][d]*w;
  }
  #pragma unroll
  for (int b = 0; b < 8; b++) out[(long)b*VOC + v] = acc[b];
}

extern "C" void kernel_launch(void* const* d_in, const int* in_sizes, int n_in,
                              void* d_out, int out_size, void* d_ws, size_t ws_size,
                              hipStream_t stream){
  const int*   tokens = (const int*)d_in[0];
  const float* embed  = (const float*)d_in[1];
  const float* ln1_g  = (const float*)d_in[2];
  const float* ln1_b  = (const float*)d_in[3];
  const float* ln2_g  = (const float*)d_in[4];
  const float* ln2_b  = (const float*)d_in[5];
  const float* W1     = (const float*)d_in[6];
  const float* b1     = (const float*)d_in[7];
  const float* W2     = (const float*)d_in[8];
  const float* b2     = (const float*)d_in[9];
  const float* Wout   = (const float*)d_in[10];
  const float* bout   = (const float*)d_in[11];
  float* out = (float*)d_out;

  char* p = (char*)d_ws;
  size_t off = 0;
  auto alloc = [&](size_t bytes)->char*{
    char* r = p + off; off += (bytes + 255) & ~(size_t)255; return r;
  };
  float* x   = (float*)alloc((size_t)ROWS*DD*4);     // f32 residual stream
  u16*   h   = (u16*)  alloc((size_t)ROWS*DD*2);     // LN output bf16
  u16*  gbuf = (u16*)  alloc((size_t)ROWS*DFF*2);    // MLP hidden; aliased as F
  u16*  dftD = (u16*)  alloc((size_t)1536*768*2);
  u16*  dftS = (u16*)  alloc((size_t)2048*4096*2);
  u16*  w1t  = (u16*)  alloc((size_t)DFF*DD*2);
  u16*  w2t  = (u16*)  alloc((size_t)DD*DFF*2);
  if (off > ws_size) return;
  u16* F = gbuf;

  k_dftD<<<(1536*768+255)/256, 256, 0, stream>>>(dftD);
  k_dftS<<<(2048*4096+255)/256, 256, 0, stream>>>(dftS);
  k_embed<<<(ROWS*192+255)/256, 256, 0, stream>>>(tokens, (const float4*)embed, (float4*)x);

  for (int l = 0; l < NL; l++){
    k_ln<<<ROWS/4, 256, 0, stream>>>(x, ln1_g + l*DD, ln1_b + l*DD, h);
    // yc|ys = h @ [C_D^T | S_D^T], written transposed into F  (M=16384,N=1536,K=768)
    k_gemm128<EPI_DFT><<<128*12, 256, 0, stream>>>(
        h, dftD, 128, 1536, 768, 12, 0, 0, 0, nullptr, nullptr, F);
    // x += [C_S | -S_S] @ [yc ; ys]  (M=2048,N=768,K=4096, batched over 8)
    k_gemm128<EPI_ADDX><<<dim3(16*6, 1, 8), 256, 0, stream>>>(
        dftS, F, 16, 768, 4096, 64, 0, (long)768*4096, 2048, x, nullptr, nullptr);
    k_ln<<<ROWS/4, 256, 0, stream>>>(x, ln2_g + l*DD, ln2_b + l*DD, h);
    k_transpose_cvt<<<dim3(DFF/32, DD/32), dim3(32,8), 0, stream>>>(
        W1 + (long)l*DD*DFF, w1t, DD, DFF);
    k_transpose_cvt<<<dim3(DD/32, DFF/32), dim3(32,8), 0, stream>>>(
        W2 + (long)l*DFF*DD, w2t, DFF, DD);
    // g = gelu(h @ W1 + b1)  (M=16384,N=3072,K=768)
    k_gemm128<EPI_GELU><<<128*24, 256, 0, stream>>>(
        h, w1t, 128, 3072, 768, 12, 0, 0, 0, nullptr, b1 + l*DFF, gbuf);
    // x += g @ W2 + b2  (M=16384,N=768,K=3072)
    k_gemm128<EPI_ADDX><<<128*6, 256, 0, stream>>>(
        gbuf, w2t, 128, 768, 3072, 48, 0, 0, 0, x, b2 + l*DD, nullptr);
  }
  k_logits<<<VOC/256, 256, 0, stream>>>(x, Wout, bout, out);
}

// Round 10
// 5202.661 us; speedup vs baseline: 1.1951x; 1.1951x over previous
//
#include <hip/hip_runtime.h>
#include <hip/hip_bf16.h>

typedef unsigned short u16;
typedef __attribute__((ext_vector_type(8))) __bf16 bf16x8;
typedef __attribute__((ext_vector_type(4))) float f32x4;
typedef __attribute__((ext_vector_type(4))) unsigned short u16x4;

#define BB 8
#define SS 2048
#define DD 768
#define DFF 3072
#define NL 12
#define ROWS (BB*SS)
#define VOC 32000

__device__ __forceinline__ u16 f2bf(float f){
  union { float f; unsigned u; } v; v.f = f;
  unsigned u = v.u;
  u += 0x7FFF + ((u >> 16) & 1);
  return (u16)(u >> 16);
}
__device__ __forceinline__ float bf2f(u16 b){
  union { unsigned u; float f; } v; v.u = ((unsigned)b) << 16; return v.f;
}

// ---------- setup kernels ----------
__global__ void k_embed(const int* __restrict__ tok, const float4* __restrict__ emb,
                        float4* __restrict__ x){
  int i = blockIdx.x*256 + threadIdx.x;
  if (i >= ROWS*192) return;
  int row = i/192, c = i - row*192;
  x[i] = emb[(long)tok[row]*192 + c];
}

__global__ void k_dftD(u16* __restrict__ out){ // [1536][768]: rows<768 cos, >=768 sin
  int i = blockIdx.x*256 + threadIdx.x;
  if (i >= 1536*768) return;
  int n = i/768, k = i - n*768;
  int nn = (n < 768) ? n : n - 768;
  int m = (nn*k) % 768;
  float a = 2.0f*(float)m/768.0f;
  out[i] = f2bf((n < 768) ? cospif(a) : sinpif(a));
}

// folded S-DFT [2048][2048]: slot<=1024 -> cos(2*pi*t*slot/2048); slot>1024 -> -sin(2*pi*t*(slot-1024)/2048)
__global__ void k_dftS2(u16* __restrict__ out){
  int i = blockIdx.x*256 + threadIdx.x;
  if (i >= 2048*2048) return;
  int t = i >> 11, slot = i & 2047;
  int ss = (slot <= 1024) ? slot : slot - 1024;
  int m = (t*ss) & 2047;
  float a = (float)m * (1.0f/1024.0f);
  out[i] = f2bf((slot <= 1024) ? cospif(a) : -sinpif(a));
}

// Fold F[b][d][4096] -> Ff[b][d][2048]:
//   slot 0       : yc[0]
//   slot 1..1023 : yc[s] + yc[2048-s]
//   slot 1024    : yc[1024]
//   slot 1025+   : ys[ss] - ys[2048-ss]   (ss = slot-1024; ys at F[2048+..])
__global__ void k_fold(const u16* __restrict__ F, u16* __restrict__ Ff){
  long i = (long)blockIdx.x*256 + threadIdx.x;
  if (i >= (long)BB*768*2048) return;
  int slot = (int)(i & 2047);
  long bd = i >> 11;
  const u16* src = F + bd*4096;
  float v;
  if (slot == 0)         v = bf2f(src[0]);
  else if (slot < 1024)  v = bf2f(src[slot]) + bf2f(src[2048 - slot]);
  else if (slot == 1024) v = bf2f(src[1024]);
  else { int ss = slot - 1024; v = bf2f(src[2048 + ss]) - bf2f(src[4096 - ss]); }
  Ff[i] = f2bf(v);
}

// one wave per row of 768
__global__ void k_ln(const float* __restrict__ x, const float* __restrict__ g,
                     const float* __restrict__ b, u16* __restrict__ h){
  int row = blockIdx.x*4 + (threadIdx.x >> 6);
  int lane = threadIdx.x & 63;
  const float* xr = x + (long)row*DD;
  float v[12];
  float s = 0.f;
  #pragma unroll
  for (int j = 0; j < 12; j++){ v[j] = xr[lane + j*64]; s += v[j]; }
  #pragma unroll
  for (int o = 32; o > 0; o >>= 1) s += __shfl_xor(s, o);
  float mu = s * (1.0f/768.0f);
  float q = 0.f;
  #pragma unroll
  for (int j = 0; j < 12; j++){ float d = v[j]-mu; q += d*d; }
  #pragma unroll
  for (int o = 32; o > 0; o >>= 1) q += __shfl_xor(q, o);
  float rs = rsqrtf(q * (1.0f/768.0f) + 1e-5f);
  u16* hr = h + (long)row*DD;
  #pragma unroll
  for (int j = 0; j < 12; j++){
    int e = lane + j*64;
    hr[e] = f2bf((v[j]-mu)*rs*g[e] + b[e]);
  }
}

// f32 [R][C] -> bf16 [C][R]
__global__ void k_transpose_cvt(const float* __restrict__ src, u16* __restrict__ dst,
                                int R, int C){
  __shared__ float t[32][33];
  int bx = blockIdx.x*32, by = blockIdx.y*32;
  int tx = threadIdx.x, ty = threadIdx.y;
  #pragma unroll
  for (int i = 0; i < 4; i++) t[ty+i*8][tx] = src[(long)(by+ty+i*8)*C + bx+tx];
  __syncthreads();
  #pragma unroll
  for (int i = 0; i < 4; i++) dst[(long)(bx+ty+i*8)*R + by+tx] = f2bf(t[tx][ty+i*8]);
}

#define EPI_DFT  0
#define EPI_ADDX 1
#define EPI_GELU 2

// ---------- 256^2 double-buffered GEMM, R7-proven (full __syncthreads drain) ----------
#define MFMA_Q(H, G, BF) do { \
  __builtin_amdgcn_s_setprio(1); \
  _Pragma("unroll") \
  for (int mm = 0; mm < 4; ++mm) \
    _Pragma("unroll") \
    for (int nn = 0; nn < 2; ++nn) \
      _Pragma("unroll") \
      for (int ks = 0; ks < 2; ++ks) \
        acc[((H)<<2)+mm][((G)<<1)+nn] = __builtin_amdgcn_mfma_f32_16x16x32_bf16( \
            aF[mm][ks], BF[nn][ks], acc[((H)<<2)+mm][((G)<<1)+nn], 0, 0, 0); \
  __builtin_amdgcn_s_setprio(0); \
} while(0)

template<int EPI>
__global__ __launch_bounds__(512, 2)
void k_gemm256(const u16* __restrict__ A, const u16* __restrict__ BT,
               int Mt, int N, int K, int NT, long aBS, long btBS, int rowOffPerZ,
               float* __restrict__ X, const float* __restrict__ bias,
               u16* __restrict__ OUT){
  __shared__ __align__(16) u16 lds[2][2][256][64];   // [buf][A/B][row][col] = 128 KiB
  const int tid  = threadIdx.x;
  const int wave = tid >> 6, lane = tid & 63;
  const int wm = wave >> 2, wn = wave & 3;

  const int bz = blockIdx.z;
  const u16* Ab = A + (long)bz*aBS;
  const u16* Bb = BT + (long)bz*btBS;
  const int rowOff = bz*rowOffPerZ;

  // XCD-aware swizzle (gridDim.x % 8 == 0 at all call sites)
  const int nwg = gridDim.x;
  const int id  = blockIdx.x;
  const int sw  = (id & 7) * (nwg >> 3) + (id >> 3);
  const int bm = (sw % Mt) << 8;
  const int bn = (sw / Mt) << 8;

  const int fr   = lane & 15;
  const int fks8 = (lane >> 4) << 3;
  const int swz  = (fr & 7) << 3;             // read-side XOR (elements)

  const int sRow = (wave << 3) + (lane >> 3); // staging row within half
  const int sCol = ((lane & 7) ^ ((lane >> 3) & 7)) << 3; // pre-swizzled src col chunk

  f32x4 acc[8][4] = {};
  bf16x8 aF[4][2], b0F[2][2], b1F[2][2];

  auto stage = [&](int tile){               // stage full tile (4 halves) into buf tile&1
    if (tile >= NT) return;
    #pragma unroll
    for (int h = 0; h < 4; ++h){
      const int isB   = ((h + 1) >> 1) & 1;
      const int rhalf = ((h >> 1) & 1) << 7;
      const u16* src = isB ? Bb : Ab;
      const int rb = (isB ? bn : bm) + rhalf + sRow;
      const u16* s0 = src + (long)rb * K + (tile << 6) + sCol;
      u16* d0 = &lds[tile & 1][isB][rhalf + (wave << 3)][0];
      __builtin_amdgcn_global_load_lds((__attribute__((address_space(1))) void*)(s0),
                                       (__attribute__((address_space(3))) void*)(d0), 16, 0, 0);
      __builtin_amdgcn_global_load_lds((__attribute__((address_space(1))) void*)(s0 + ((long)K << 6)),
                                       (__attribute__((address_space(3))) void*)(d0 + 64*64), 16, 0, 0);
    }
  };

  auto readA = [&](int c, int H){
    const u16* base = &lds[c][0][(H << 7) + (wm << 6)][0];
    #pragma unroll
    for (int mm = 0; mm < 4; ++mm)
      #pragma unroll
      for (int ks = 0; ks < 2; ++ks)
        aF[mm][ks] = *(const bf16x8*)&base[((mm<<4) + fr)*64 + (((ks<<5) + fks8) ^ swz)];
  };
  auto readB = [&](int c, int G, bf16x8 (&bF)[2][2]){
    const u16* base = &lds[c][1][(G << 7) + (wn << 5)][0];
    #pragma unroll
    for (int nn = 0; nn < 2; ++nn)
      #pragma unroll
      for (int ks = 0; ks < 2; ++ks)
        bF[nn][ks] = *(const bf16x8*)&base[((nn<<4) + fr)*64 + (((ks<<5) + fks8) ^ swz)];
  };

  stage(0);
  __syncthreads();                           // full drain: tile 0 resident

  int c = 0;
  for (int T = 0; T < NT; ++T, c ^= 1){
    stage(T + 1);                            // async into buf c^1, drained by end barrier
    readA(c, 0); readB(c, 0, b0F);
    MFMA_Q(0, 0, b0F);
    readB(c, 1, b1F);
    MFMA_Q(0, 1, b1F);
    readA(c, 1);
    MFMA_Q(1, 1, b1F);
    MFMA_Q(1, 0, b0F);
    __syncthreads();                         // drains vmcnt+lgkmcnt: T+1 resident, reads done
  }

  const int er = (lane >> 4) << 2, ec = lane & 15;
  #pragma unroll
  for (int mi = 0; mi < 8; ++mi){
    int row = bm + ((mi >> 2) << 7) + (wm << 6) + ((mi & 3) << 4) + er;
    #pragma unroll
    for (int ni = 0; ni < 4; ++ni){
      int col = bn + ((ni >> 1) << 7) + (wn << 5) + ((ni & 1) << 4) + ec;
      f32x4 v = acc[mi][ni];
      if constexpr (EPI == EPI_ADDX){
        float bv = bias ? bias[col] : 0.0f;
        #pragma unroll
        for (int r = 0; r < 4; r++)
          X[(long)(rowOff + row + r)*N + col] += v[r] + bv;
      } else if constexpr (EPI == EPI_GELU){
        float bv = bias[col];
        #pragma unroll
        for (int r = 0; r < 4; r++){
          float tt = v[r] + bv;
          OUT[(long)(row + r)*N + col] = f2bf(0.5f*tt*(1.0f + erff(tt*0.70710678118654752f)));
        }
      } else { // EPI_DFT: write transposed per batch into F[b][d][slot]
        int bb = row >> 11, s = row & 2047;
        int d, slot;
        if (col < 768){ d = col; slot = s; } else { d = col - 768; slot = 2048 + s; }
        u16x4 pk;
        #pragma unroll
        for (int r = 0; r < 4; r++) pk[r] = f2bf(v[r]);
        *(u16x4*)&OUT[((long)(bb*768 + d))*4096 + slot] = pk;
      }
    }
  }
}

__global__ void k_logits(const float* __restrict__ x, const float* __restrict__ Wout,
                         const float* __restrict__ bout, float* __restrict__ out){
  __shared__ float xl[8][768];
  int tid = threadIdx.x;
  for (int i = tid; i < 8*768; i += 256){
    int b = i/768, d = i - b*768;
    xl[b][d] = x[((long)(b*2048 + 2047))*768 + d];
  }
  __syncthreads();
  int v = blockIdx.x*256 + tid;
  float acc[8];
  float bv = bout[v];
  #pragma unroll
  for (int b = 0; b < 8; b++) acc[b] = bv;
  for (int d = 0; d < 768; d++){
    float w = Wout[(long)d*VOC + v];
    #pragma unroll
    for (int b = 0; b < 8; b++) acc[b] += xl[b][d]*w;
  }
  #pragma unroll
  for (int b = 0; b < 8; b++) out[(long)b*VOC + v] = acc[b];
}

extern "C" void kernel_launch(void* const* d_in, const int* in_sizes, int n_in,
                              void* d_out, int out_size, void* d_ws, size_t ws_size,
                              hipStream_t stream){
  const int*   tokens = (const int*)d_in[0];
  const float* embed  = (const float*)d_in[1];
  const float* ln1_g  = (const float*)d_in[2];
  const float* ln1_b  = (const float*)d_in[3];
  const float* ln2_g  = (const float*)d_in[4];
  const float* ln2_b  = (const float*)d_in[5];
  const float* W1     = (const float*)d_in[6];
  const float* b1     = (const float*)d_in[7];
  const float* W2     = (const float*)d_in[8];
  const float* b2     = (const float*)d_in[9];
  const float* Wout   = (const float*)d_in[10];
  const float* bout   = (const float*)d_in[11];
  float* out = (float*)d_out;

  char* p = (char*)d_ws;
  size_t off = 0;
  auto alloc = [&](size_t bytes)->char*{
    char* r = p + off; off += (bytes + 255) & ~(size_t)255; return r;
  };
  float* x   = (float*)alloc((size_t)ROWS*DD*4);     // f32 residual stream
  u16*   h   = (u16*)  alloc((size_t)ROWS*DD*2);     // LN output bf16
  u16*  gbuf = (u16*)  alloc((size_t)ROWS*DFF*2);    // MLP hidden; F head + Ff in tail
  u16*  dftD = (u16*)  alloc((size_t)1536*768*2);
  u16*  dftS2= (u16*)  alloc((size_t)2048*2048*2);
  u16*  w1t  = (u16*)  alloc((size_t)DFF*DD*2);
  u16*  w2t  = (u16*)  alloc((size_t)DD*DFF*2);
  if (off > ws_size) return;
  u16* F  = gbuf;                                 // [8][768][4096] = 50.3 MB
  u16* Ff = gbuf + (size_t)BB*768*4096;           // [8][768][2048] = 25.2 MB (dead tail of gbuf)

  k_dftD<<<(1536*768+255)/256, 256, 0, stream>>>(dftD);
  k_dftS2<<<(2048*2048+255)/256, 256, 0, stream>>>(dftS2);
  k_embed<<<(ROWS*192+255)/256, 256, 0, stream>>>(tokens, (const float4*)embed, (float4*)x);

  for (int l = 0; l < NL; l++){
    k_ln<<<ROWS/4, 256, 0, stream>>>(x, ln1_g + l*DD, ln1_b + l*DD, h);
    // yc|ys = h @ [C_D^T | S_D^T], written transposed into F  (M=16384,N=1536,K=768)
    k_gemm256<EPI_DFT><<<64*6, 512, 0, stream>>>(
        h, dftD, 64, 1536, 768, 12, 0, 0, 0, nullptr, nullptr, F);
    // fold K: Ff[b][d][0..2047] from F[b][d][0..4095]  (exact cos/sin symmetry)
    k_fold<<<(int)(((long)BB*768*2048 + 255)/256), 256, 0, stream>>>(F, Ff);
    // x += dftS2 @ Ff  (M=2048,N=768,K=2048, batched over 8)
    k_gemm256<EPI_ADDX><<<dim3(8*3, 1, 8), 512, 0, stream>>>(
        dftS2, Ff, 8, 768, 2048, 32, 0, (long)768*2048, 2048, x, nullptr, nullptr);
    k_ln<<<ROWS/4, 256, 0, stream>>>(x, ln2_g + l*DD, ln2_b + l*DD, h);
    k_transpose_cvt<<<dim3(DFF/32, DD/32), dim3(32,8), 0, stream>>>(
        W1 + (long)l*DD*DFF, w1t, DD, DFF);
    k_transpose_cvt<<<dim3(DD/32, DFF/32), dim3(32,8), 0, stream>>>(
        W2 + (long)l*DFF*DD, w2t, DFF, DD);
    // g = gelu(h @ W1 + b1)  (M=16384,N=3072,K=768)
    k_gemm256<EPI_GELU><<<64*12, 512, 0, stream>>>(
        h, w1t, 64, 3072, 768, 12, 0, 0, 0, nullptr, b1 + l*DFF, gbuf);
    // x += g @ W2 + b2  (M=16384,N=768,K=3072)
    k_gemm256<EPI_ADDX><<<64*3, 512, 0, stream>>>(
        gbuf, w2t, 64, 768, 3072, 48, 0, 0, 0, x, b2 + l*DD, nullptr);
  }
  k_logits<<<VOC/256, 256, 0, stream>>>(x, Wout, bout, out);
}